// Round 9
// baseline (1000.757 us; speedup 1.0000x reference)
//
#include <hip/hip_runtime.h>
#include <math.h>

#define BB 4
#define NN 4995
#define CC 128
#define IMG 224
#define IMGP (IMG*IMG)
#define ALPHA_F 100.0f
#define SPLITS 8
#define COLS_PER_SPLIT 640   // 32-aligned; 8*640=5120 >= 4995
#define RBLK 40              // ceil(4995/128)
#define NG 158               // col groups of 32 (incl. 1 pad group)
#define TKCAND 512

// ws layout in float units
#define OFF_V12    0            // 59940
#define OFF_FN1    60000        // 19980
#define OFF_V1Q    81000        // 79920 {x,y,z,|v1|^2}
#define OFF_V2Q    161000       // 79920 {x,y,z,|v2|^2}
#define OFF_C2Q    241000       // 79920 {x,y,z,|f2|^2}
#define OFF_PART   321000       // 19980*8*5 = 799200 -> ends 1120200
#define OFF_IMG1   1121000      // 200704
#define OFF_IMG2   1321704      // 200704 -> ends 1522408
#define OFF_ACC    1522408      // 3*64 f64 = 384 floats (byte 6089632, 8-aligned)
#define OFF_STATS  1522792      // 128 -> ends 1522920
#define OFF_F2H    1523000      // 4*158*4096 shorts = 1294336 floats
#define OFF_F2L    2818000      // 1294336 floats -> ends 4112336 (16.45MB)
#define OFF_F1H    4113000      // 4*40*4*4096 shorts = 1310720 floats
#define OFF_F1L    5424000      // 1310720 floats -> ends 6734720 (26.9MB)
#define WS_NEED_PRE ((size_t)6735000*sizeof(float))
#define ZERO_START OFF_IMG1
#define ZERO_FLOATS (1522920 - OFF_IMG1)

typedef short v8s  __attribute__((ext_vector_type(8)));
typedef float v16f __attribute__((ext_vector_type(16)));

__device__ __forceinline__ float wave_min(float v){
#pragma unroll
  for (int off=32; off; off>>=1) v = fminf(v, __shfl_xor(v, off));
  return v;
}
__device__ __forceinline__ float wave_sum(float v){
#pragma unroll
  for (int off=32; off; off>>=1) v += __shfl_xor(v, off);
  return v;
}

// pack top-16 bits (bf16 truncation) of two floats: (hi16(b)<<16)|hi16(a)
__device__ __forceinline__ int pack_bf_hi(float a, float b){
  return (int)__builtin_amdgcn_perm(__float_as_uint(b), __float_as_uint(a), 0x07060302u);
}

// split 8 consecutive floats (a=k..k+3, c=k+4..k+7) into bf16 hi + lo int4s
__device__ __forceinline__ void cvt_hilo(float4 a, float4 c, int4& hi, int4& lo){
  float hx=__uint_as_float(__float_as_uint(a.x)&0xffff0000u);
  float hy=__uint_as_float(__float_as_uint(a.y)&0xffff0000u);
  float hz=__uint_as_float(__float_as_uint(a.z)&0xffff0000u);
  float hw=__uint_as_float(__float_as_uint(a.w)&0xffff0000u);
  float gx=__uint_as_float(__float_as_uint(c.x)&0xffff0000u);
  float gy=__uint_as_float(__float_as_uint(c.y)&0xffff0000u);
  float gz=__uint_as_float(__float_as_uint(c.z)&0xffff0000u);
  float gw=__uint_as_float(__float_as_uint(c.w)&0xffff0000u);
  hi = make_int4(pack_bf_hi(a.x,a.y), pack_bf_hi(a.z,a.w),
                 pack_bf_hi(c.x,c.y), pack_bf_hi(c.z,c.w));
  lo = make_int4(pack_bf_hi(a.x-hx,a.y-hy), pack_bf_hi(a.z-hz,a.w-hw),
                 pack_bf_hi(c.x-gx,c.y-gy), pack_bf_hi(c.z-gz,c.w-gw));
}

// ---------------- norms + packed quads ----------------
__global__ void k_norms(const float* __restrict__ verts1, const float* __restrict__ verts2,
                        const float* __restrict__ feat1, const float* __restrict__ feat2,
                        float* __restrict__ ws) {
  int i = blockIdx.x*blockDim.x + threadIdx.x;
  if (i >= BB*NN) return;
  float x=verts1[(size_t)i*3], y=verts1[(size_t)i*3+1], z=verts1[(size_t)i*3+2];
  ((float4*)(ws+OFF_V1Q))[i] = make_float4(x,y,z, x*x+y*y+z*z);
  float x2=verts2[(size_t)i*3], y2=verts2[(size_t)i*3+1], z2=verts2[(size_t)i*3+2];
  ((float4*)(ws+OFF_V2Q))[i] = make_float4(x2,y2,z2, x2*x2+y2*y2+z2*z2);
  {
    const float4* f = (const float4*)(feat2 + (size_t)i*CC);
    float s0=0.f,s1=0.f,s2=0.f,s3=0.f;
#pragma unroll
    for (int k=0;k<CC/4;k++){ float4 t=f[k];
      s0=fmaf(t.x,t.x,s0); s1=fmaf(t.y,t.y,s1); s2=fmaf(t.z,t.z,s2); s3=fmaf(t.w,t.w,s3); }
    ((float4*)(ws+OFF_C2Q))[i] = make_float4(x2,y2,z2, (s0+s1)+(s2+s3));
  }
  {
    const float4* f = (const float4*)(feat1 + (size_t)i*CC);
    float s0=0.f,s1=0.f,s2=0.f,s3=0.f;
#pragma unroll
    for (int k=0;k<CC/4;k++){ float4 t=f[k];
      s0=fmaf(t.x,t.x,s0); s1=fmaf(t.y,t.y,s1); s2=fmaf(t.z,t.z,s2); s3=fmaf(t.w,t.w,s3); }
    ws[OFF_FN1+i] = (s0+s1)+(s2+s3);
  }
}

// ---------------- pre-convert feat2 -> tiled bf16 hi/lo ----------------
// layout [b][g][kt4][kh2][half2][c32][j8], strides (shorts): j=1,c32=8,half=256,kh=512,kt=1024,g=4096
__global__ __launch_bounds__(256) void k_conv(const float* __restrict__ feat2, float* __restrict__ ws) {
  int g = blockIdx.x, b = blockIdx.y;
  int t = threadIdx.x;
  int q = t >> 5, c32 = t & 31;
  int col = g*32 + c32; if (col > NN-1) col = NN-1;
  const float4* src = (const float4*)(feat2 + ((size_t)(b*NN + col))*CC) + q*4;
  float4 v0 = src[0], v1 = src[1], v2 = src[2], v3 = src[3];
  short* f2h = (short*)(ws + OFF_F2H);
  short* f2l = (short*)(ws + OFF_F2L);
  size_t base = ((size_t)(b*NG + g))*4096 + (size_t)q*512 + c32*8;
  int4 hi, lo;
  cvt_hilo(v0, v1, hi, lo);
  *(int4*)&f2h[base] = hi;  *(int4*)&f2l[base] = lo;
  cvt_hilo(v2, v3, hi, lo);
  *(int4*)&f2h[base + 256] = hi;  *(int4*)&f2l[base + 256] = lo;
}

// ---------------- pre-convert feat1 -> tiled bf16 hi/lo ----------------
// layout [b][rblk40][kt4][gg4][kh2][half2][r32][j8]; chunk cid = t (16B chunks)
__global__ __launch_bounds__(256) void k_conv1(const float* __restrict__ feat1, float* __restrict__ ws) {
  int rblk = blockIdx.x, b = blockIdx.y;
  int t = threadIdx.x;
  int gg = t >> 7, kh = (t >> 6) & 1, half = (t >> 5) & 1, r32 = t & 31;
  int row = rblk*128 + gg*32 + r32; if (row > NN-1) row = NN-1;
  const float* src = feat1 + ((size_t)b*NN + row)*CC;
  short* f1h = (short*)(ws + OFF_F1H);
  short* f1l = (short*)(ws + OFF_F1L);
#pragma unroll
  for (int kt=0; kt<4; kt++){
    int k0 = kt*32 + kh*16 + half*8;
    float4 v0 = *(const float4*)(src + k0);
    float4 v1 = *(const float4*)(src + k0 + 4);
    int4 hi, lo;
    cvt_hilo(v0, v1, hi, lo);
    size_t base = ((size_t)((b*RBLK + rblk)*4) + kt)*4096 + (size_t)t*8;
    *(int4*)&f1h[base] = hi;
    *(int4*)&f1l[base] = lo;
  }
}

// ---------------- stage A (pre-converted A+B): MFMA GEMM + in-lane online softmax ----------------
__global__ __launch_bounds__(256) void k_stageA_pre(float* __restrict__ ws) {
  __shared__ __align__(16) short Ah[4096], Al[4096];   // feat1: [gg4][kh2][half2][r32][j8]
  __shared__ __align__(16) short Bh[2048], Bl[2048];   // feat2: [cg2][kh2][half2][c32][j8]
  __shared__ __align__(16) float colq[64*4];           // {x,y,z,fn2} per col

  int rblk  = blockIdx.x;
  int split = blockIdx.y;
  int b     = blockIdx.z;
  int rowBase = rblk*128;
  int colBase = split*COLS_PER_SPLIT;
  int colEnd  = colBase + COLS_PER_SPLIT; if (colEnd > NN) colEnd = NN;
  int nct = (colEnd - colBase + 63) >> 6;

  int t    = threadIdx.x;
  int w    = t >> 6;
  int lane = t & 63;
  int half = lane >> 5;
  int m32  = lane & 31;

  const short* f2h = (const short*)(ws + OFF_F2H);
  const short* f2l = (const short*)(ws + OFF_F2L);
  const short* f1h = (const short*)(ws + OFF_F1H);
  const short* f1l = (const short*)(ws + OFF_F1L);
  const float4* c2q = (const float4*)(ws + OFF_C2Q) + (size_t)b*NN;

  int nrow = rowBase + w*32 + m32;
  int nclamp = nrow > NN-1 ? NN-1 : nrow;
  float sn = ws[OFF_FN1 + (size_t)b*NN + nclamp];

  int scg = t >> 7;
  size_t bDstOff = (size_t)scg*1024 + (t & 127)*8;
  size_t aOff = (size_t)t*8;

  float mm = -INFINITY, S = 0.f, Vx = 0.f, Vy = 0.f, Vz = 0.f;

  for (int ci = 0; ci < nct; ci++){
    int ctBase = colBase + ci*64;
    int g0 = ctBase >> 5;
    __syncthreads();
    if (t < 64){
      int c = ctBase + t; if (c > NN-1) c = NN-1;
      *(float4*)&colq[t*4] = c2q[c];
    }
    v16f acc0, acc1;
#pragma unroll
    for (int i=0;i<16;i++){ acc0[i]=0.f; acc1[i]=0.f; }

#pragma unroll 1
    for (int kt = 0; kt < 4; kt++){
      __syncthreads();
      // B (feat2) staging: 2 x b128 copy
      {
        size_t gsrc = ((size_t)(b*NG + g0 + scg))*4096 + (size_t)kt*1024 + (t & 127)*8;
        int4 vh = *(const int4*)&f2h[gsrc];
        int4 vl = *(const int4*)&f2l[gsrc];
        *(int4*)&Bh[bDstOff] = vh;
        *(int4*)&Bl[bDstOff] = vl;
      }
      // A (feat1) staging: 4 x b128 copy (pre-converted, no VALU)
      {
        size_t aBase = ((size_t)((b*RBLK + rblk)*4) + kt)*4096 + aOff;
        int4 h0 = *(const int4*)&f1h[aBase];
        int4 h1 = *(const int4*)&f1h[aBase + 2048];
        int4 l0 = *(const int4*)&f1l[aBase];
        int4 l1 = *(const int4*)&f1l[aBase + 2048];
        *(int4*)&Ah[aOff]        = h0;
        *(int4*)&Ah[aOff + 2048] = h1;
        *(int4*)&Al[aOff]        = l0;
        *(int4*)&Al[aOff + 2048] = l1;
      }
      __syncthreads();
#pragma unroll
      for (int kh=0; kh<2; kh++){
        size_t fo = (size_t)kh*512 + (size_t)half*256 + m32*8;
        v8s b1h = *(const v8s*)&Ah[(size_t)w*1024 + fo];
        v8s b1l = *(const v8s*)&Al[(size_t)w*1024 + fo];
        v8s a0h = *(const v8s*)&Bh[fo];
        v8s a0l = *(const v8s*)&Bl[fo];
        v8s a1h = *(const v8s*)&Bh[1024 + fo];
        v8s a1l = *(const v8s*)&Bl[1024 + fo];
        acc0 = __builtin_amdgcn_mfma_f32_32x32x16_bf16(a0h, b1h, acc0, 0,0,0);
        acc0 = __builtin_amdgcn_mfma_f32_32x32x16_bf16(a0h, b1l, acc0, 0,0,0);
        acc0 = __builtin_amdgcn_mfma_f32_32x32x16_bf16(a0l, b1h, acc0, 0,0,0);
        acc1 = __builtin_amdgcn_mfma_f32_32x32x16_bf16(a1h, b1h, acc1, 0,0,0);
        acc1 = __builtin_amdgcn_mfma_f32_32x32x16_bf16(a1h, b1l, acc1, 0,0,0);
        acc1 = __builtin_amdgcn_mfma_f32_32x32x16_bf16(a1l, b1h, acc1, 0,0,0);
      }
    }

    float Mt = -INFINITY;
#pragma unroll
    for (int reg=0; reg<16; reg++){
      int cp0 = (reg&3) + 8*(reg>>2) + 4*half;
      float f0 = colq[cp0*4+3];
      float d0 = fmaf(-2.f, acc0[reg], sn) + f0;
      float l0 = (ctBase+cp0 < colEnd) ? (-ALPHA_F*sqrtf(fmaxf(d0,1e-12f))) : -INFINITY;
      acc0[reg] = l0; Mt = fmaxf(Mt, l0);
      int cp1 = cp0 + 32;
      float f1v = colq[cp1*4+3];
      float d1 = fmaf(-2.f, acc1[reg], sn) + f1v;
      float l1 = (ctBase+cp1 < colEnd) ? (-ALPHA_F*sqrtf(fmaxf(d1,1e-12f))) : -INFINITY;
      acc1[reg] = l1; Mt = fmaxf(Mt, l1);
    }
    float mn = fmaxf(mm, Mt);
    float sc = __expf(mm - mn);
    float se=0.f, sx=0.f, sy=0.f, sz=0.f;
#pragma unroll
    for (int reg=0; reg<16; reg++){
      int cp0 = (reg&3) + 8*(reg>>2) + 4*half;
      float4 q0 = *(const float4*)&colq[cp0*4];
      float e0 = __expf(acc0[reg] - mn);
      se += e0; sx=fmaf(e0,q0.x,sx); sy=fmaf(e0,q0.y,sy); sz=fmaf(e0,q0.z,sz);
      float4 q1 = *(const float4*)&colq[(cp0+32)*4];
      float e1 = __expf(acc1[reg] - mn);
      se += e1; sx=fmaf(e1,q1.x,sx); sy=fmaf(e1,q1.y,sy); sz=fmaf(e1,q1.z,sz);
    }
    S  = fmaf(S,  sc, se);
    Vx = fmaf(Vx, sc, sx);
    Vy = fmaf(Vy, sc, sy);
    Vz = fmaf(Vz, sc, sz);
    mm = mn;
  }

  {
    float m2  = __shfl_xor(mm, 32);
    float S2  = __shfl_xor(S,  32);
    float Vx2 = __shfl_xor(Vx, 32);
    float Vy2 = __shfl_xor(Vy, 32);
    float Vz2 = __shfl_xor(Vz, 32);
    float M = fmaxf(mm, m2);
    float c1 = __expf(mm - M), c2 = __expf(m2 - M);
    float Sf  = S*c1  + S2*c2;
    float Vxf = Vx*c1 + Vx2*c2;
    float Vyf = Vy*c1 + Vy2*c2;
    float Vzf = Vz*c1 + Vz2*c2;
    if (half==0 && nrow < NN){
      float* p = ws + OFF_PART + ((size_t)(b*NN+nrow)*SPLITS + split)*5;
      p[0]=M; p[1]=Sf; p[2]=Vxf; p[3]=Vyf; p[4]=Vzf;
    }
  }
}

// ---------------- stage A fallback (in-kernel A conversion) — used if ws too small ----------------
__global__ __launch_bounds__(256) void k_stageA_fb(const float* __restrict__ feat1,
      float* __restrict__ ws) {
  __shared__ __align__(16) short Ah[4096], Al[4096];
  __shared__ __align__(16) short Bh[2048], Bl[2048];
  __shared__ __align__(16) float colq[64*4];

  int rblk  = blockIdx.x;
  int split = blockIdx.y;
  int b     = blockIdx.z;
  int rowBase = rblk*128;
  int colBase = split*COLS_PER_SPLIT;
  int colEnd  = colBase + COLS_PER_SPLIT; if (colEnd > NN) colEnd = NN;
  int nct = (colEnd - colBase + 63) >> 6;

  int t    = threadIdx.x;
  int w    = t >> 6;
  int lane = t & 63;
  int half = lane >> 5;
  int m32  = lane & 31;

  const float* f1b = feat1 + (size_t)b*NN*CC;
  const short* f2h = (const short*)(ws + OFF_F2H);
  const short* f2l = (const short*)(ws + OFF_F2L);
  const float4* c2q = (const float4*)(ws + OFF_C2Q) + (size_t)b*NN;

  int nrow = rowBase + w*32 + m32;
  int nclamp = nrow > NN-1 ? NN-1 : nrow;
  float sn = ws[OFF_FN1 + (size_t)b*NN + nclamp];

  int sr = t >> 1, skh = t & 1;
  int srow = rowBase + sr; if (srow > NN-1) srow = NN-1;
  int sgg = sr >> 5, sr32 = sr & 31;
  const float4* aSrcBase = (const float4*)(f1b + (size_t)srow*CC);
  size_t aDst = (size_t)sgg*1024 + (size_t)skh*512 + sr32*8;

  int scg = t >> 7;
  size_t bDstOff = (size_t)scg*1024 + (t & 127)*8;

  float mm = -INFINITY, S = 0.f, Vx = 0.f, Vy = 0.f, Vz = 0.f;

  for (int ci = 0; ci < nct; ci++){
    int ctBase = colBase + ci*64;
    int g0 = ctBase >> 5;
    __syncthreads();
    if (t < 64){
      int c = ctBase + t; if (c > NN-1) c = NN-1;
      *(float4*)&colq[t*4] = c2q[c];
    }
    v16f acc0, acc1;
#pragma unroll
    for (int i=0;i<16;i++){ acc0[i]=0.f; acc1[i]=0.f; }

#pragma unroll 1
    for (int kt = 0; kt < 4; kt++){
      __syncthreads();
      {
        size_t gsrc = ((size_t)(b*NG + g0 + scg))*4096 + (size_t)kt*1024 + (t & 127)*8;
        int4 vh = *(const int4*)&f2h[gsrc];
        int4 vl = *(const int4*)&f2l[gsrc];
        *(int4*)&Bh[bDstOff] = vh;
        *(int4*)&Bl[bDstOff] = vl;
      }
      {
        const float4* s4 = aSrcBase + kt*8 + skh*4;
        float4 v0=s4[0], v1=s4[1], v2=s4[2], v3=s4[3];
        int4 hi, lo;
        cvt_hilo(v0, v1, hi, lo);
        *(int4*)&Ah[aDst] = hi;  *(int4*)&Al[aDst] = lo;
        cvt_hilo(v2, v3, hi, lo);
        *(int4*)&Ah[aDst + 256] = hi;  *(int4*)&Al[aDst + 256] = lo;
      }
      __syncthreads();
#pragma unroll
      for (int kh=0; kh<2; kh++){
        size_t fo = (size_t)kh*512 + (size_t)half*256 + m32*8;
        v8s b1h = *(const v8s*)&Ah[(size_t)w*1024 + fo];
        v8s b1l = *(const v8s*)&Al[(size_t)w*1024 + fo];
        v8s a0h = *(const v8s*)&Bh[fo];
        v8s a0l = *(const v8s*)&Bl[fo];
        v8s a1h = *(const v8s*)&Bh[1024 + fo];
        v8s a1l = *(const v8s*)&Bl[1024 + fo];
        acc0 = __builtin_amdgcn_mfma_f32_32x32x16_bf16(a0h, b1h, acc0, 0,0,0);
        acc0 = __builtin_amdgcn_mfma_f32_32x32x16_bf16(a0h, b1l, acc0, 0,0,0);
        acc0 = __builtin_amdgcn_mfma_f32_32x32x16_bf16(a0l, b1h, acc0, 0,0,0);
        acc1 = __builtin_amdgcn_mfma_f32_32x32x16_bf16(a1h, b1h, acc1, 0,0,0);
        acc1 = __builtin_amdgcn_mfma_f32_32x32x16_bf16(a1h, b1l, acc1, 0,0,0);
        acc1 = __builtin_amdgcn_mfma_f32_32x32x16_bf16(a1l, b1h, acc1, 0,0,0);
      }
    }

    float Mt = -INFINITY;
#pragma unroll
    for (int reg=0; reg<16; reg++){
      int cp0 = (reg&3) + 8*(reg>>2) + 4*half;
      float f0 = colq[cp0*4+3];
      float d0 = fmaf(-2.f, acc0[reg], sn) + f0;
      float l0 = (ctBase+cp0 < colEnd) ? (-ALPHA_F*sqrtf(fmaxf(d0,1e-12f))) : -INFINITY;
      acc0[reg] = l0; Mt = fmaxf(Mt, l0);
      int cp1 = cp0 + 32;
      float f1v = colq[cp1*4+3];
      float d1 = fmaf(-2.f, acc1[reg], sn) + f1v;
      float l1 = (ctBase+cp1 < colEnd) ? (-ALPHA_F*sqrtf(fmaxf(d1,1e-12f))) : -INFINITY;
      acc1[reg] = l1; Mt = fmaxf(Mt, l1);
    }
    float mn = fmaxf(mm, Mt);
    float sc = __expf(mm - mn);
    float se=0.f, sx=0.f, sy=0.f, sz=0.f;
#pragma unroll
    for (int reg=0; reg<16; reg++){
      int cp0 = (reg&3) + 8*(reg>>2) + 4*half;
      float4 q0 = *(const float4*)&colq[cp0*4];
      float e0 = __expf(acc0[reg] - mn);
      se += e0; sx=fmaf(e0,q0.x,sx); sy=fmaf(e0,q0.y,sy); sz=fmaf(e0,q0.z,sz);
      float4 q1 = *(const float4*)&colq[(cp0+32)*4];
      float e1 = __expf(acc1[reg] - mn);
      se += e1; sx=fmaf(e1,q1.x,sx); sy=fmaf(e1,q1.y,sy); sz=fmaf(e1,q1.z,sz);
    }
    S  = fmaf(S,  sc, se);
    Vx = fmaf(Vx, sc, sx);
    Vy = fmaf(Vy, sc, sy);
    Vz = fmaf(Vz, sc, sz);
    mm = mn;
  }

  {
    float m2  = __shfl_xor(mm, 32);
    float S2  = __shfl_xor(S,  32);
    float Vx2 = __shfl_xor(Vx, 32);
    float Vy2 = __shfl_xor(Vy, 32);
    float Vz2 = __shfl_xor(Vz, 32);
    float M = fmaxf(mm, m2);
    float c1 = __expf(mm - M), c2 = __expf(m2 - M);
    float Sf  = S*c1  + S2*c2;
    float Vxf = Vx*c1 + Vx2*c2;
    float Vyf = Vy*c1 + Vy2*c2;
    float Vzf = Vz*c1 + Vz2*c2;
    if (half==0 && nrow < NN){
      float* p = ws + OFF_PART + ((size_t)(b*NN+nrow)*SPLITS + split)*5;
      p[0]=M; p[1]=Sf; p[2]=Vxf; p[3]=Vyf; p[4]=Vzf;
    }
  }
}

// ---------------- combine partials -> verts12 ----------------
__global__ void k_combine(float* __restrict__ ws) {
  int row = blockIdx.x*blockDim.x + threadIdx.x;
  if (row >= BB*NN) return;
  const float* p = ws + OFF_PART + (size_t)row*SPLITS*5;
  float mm = -INFINITY;
#pragma unroll
  for (int s=0;s<SPLITS;s++) mm = fmaxf(mm, p[s*5]);
  float S=0.f,Vx=0.f,Vy=0.f,Vz=0.f;
#pragma unroll
  for (int s=0;s<SPLITS;s++){
    float sc = expf(p[s*5]-mm);
    S  += p[s*5+1]*sc; Vx += p[s*5+2]*sc; Vy += p[s*5+3]*sc; Vz += p[s*5+4]*sc;
  }
  ws[OFF_V12+(size_t)row*3+0]=Vx/S;
  ws[OFF_V12+(size_t)row*3+1]=Vy/S;
  ws[OFF_V12+(size_t)row*3+2]=Vz/S;
}

// ---------------- self-rec: 4 rows/wave, 16 rows/block ----------------
__global__ __launch_bounds__(256) void k_selfrec(float* __restrict__ ws) {
  int rblk = blockIdx.x, b = blockIdx.y;
  int lane = threadIdx.x & 63, w = threadIdx.x >> 6;
  int r0 = rblk*16 + w*4;
  const float4* v2q = (const float4*)(ws + OFF_V2Q) + (size_t)b*NN;
  const float* v12 = ws + OFF_V12 + (size_t)b*NN*3;
  float xr[4], yr[4], zr[4], sar[4]; bool val[4];
#pragma unroll
  for (int j=0;j<4;j++){
    int n = r0+j; val[j] = (n < NN); int nc = val[j] ? n : NN-1;
    xr[j]=v12[(size_t)nc*3]; yr[j]=v12[(size_t)nc*3+1]; zr[j]=v12[(size_t)nc*3+2];
    sar[j]=xr[j]*xr[j]+yr[j]*yr[j]+zr[j]*zr[j];
  }
  float mn0=INFINITY, mn1=INFINITY, mn2=INFINITY, mn3=INFINITY;
  for (int m=lane; m<NN; m+=64) {
    float4 q = v2q[m];
    mn0 = fminf(mn0, fmaf(-2.0f, xr[0]*q.x + yr[0]*q.y + zr[0]*q.z, sar[0]) + q.w);
    mn1 = fminf(mn1, fmaf(-2.0f, xr[1]*q.x + yr[1]*q.y + zr[1]*q.z, sar[1]) + q.w);
    mn2 = fminf(mn2, fmaf(-2.0f, xr[2]*q.x + yr[2]*q.y + zr[2]*q.z, sar[2]) + q.w);
    mn3 = fminf(mn3, fmaf(-2.0f, xr[3]*q.x + yr[3]*q.y + zr[3]*q.z, sar[3]) + q.w);
  }
  mn0 = wave_min(mn0); mn1 = wave_min(mn1); mn2 = wave_min(mn2); mn3 = wave_min(mn3);
  float s = (val[0]?mn0:0.f) + (val[1]?mn1:0.f) + (val[2]?mn2:0.f) + (val[3]?mn3:0.f);
  if (lane==0)
    atomicAdd(((double*)(ws+OFF_ACC)) + ((rblk*4 + w) & 63), (double)s);
}

// ---------------- top-k: ballot-radix threshold + recompute compaction + rank-count selection ----------------
__global__ __launch_bounds__(256) void k_topk(const float* __restrict__ feat1,
        const int* __restrict__ kptr, float* __restrict__ ws) {
  __shared__ unsigned int keybuf[256];
  __shared__ unsigned long long cand[TKCAND];
  __shared__ int scnt;
  __shared__ int sel[16];
  __shared__ float rs[4];
  int row = blockIdx.x;
  int t = threadIdx.x;
  int lane = t & 63, wid = t >> 6;
  int b = row / NN; int n = row - b*NN;
  int kk = *kptr; if (kk > 16) kk = 16; if (kk < 1) kk = 1;

  const float4* v1q = (const float4*)(ws + OFF_V1Q) + (size_t)b*NN;
  float4 me = v1q[n];
  float mx=-2.0f*me.x, my2=-2.0f*me.y, mz=-2.0f*me.z, sa=me.w;

  if (t==0) scnt = 0;

  unsigned int mykey = 0xFFFFFFFFu;
#pragma unroll
  for (int i=0;i<20;i++){
    int m = t + 256*i;
    if (m < NN){
      float4 q = v1q[m];
      float d2 = fmaf(mx, q.x, fmaf(my2, q.y, fmaf(mz, q.z, sa + q.w)));
      unsigned int u = __float_as_uint(d2);
      u = ((int)u < 0) ? ~u : (u ^ 0x80000000u);
      mykey = u < mykey ? u : mykey;
    }
  }
  keybuf[t] = mykey;
  __syncthreads();

  unsigned int tau;
  {
    unsigned int k0 = keybuf[lane];
    unsigned int k1 = keybuf[64+lane];
    unsigned int k2 = keybuf[128+lane];
    unsigned int k3 = keybuf[192+lane];
    unsigned int prefix = 0;
    for (int bit=31; bit>=0; --bit){
      unsigned int piv = prefix | (1u<<bit);
      int c = __popcll(__ballot(k0 < piv)) + __popcll(__ballot(k1 < piv))
            + __popcll(__ballot(k2 < piv)) + __popcll(__ballot(k3 < piv));
      if (c < kk) prefix = piv;
    }
    tau = prefix;
  }

  if (mykey <= tau){
#pragma unroll
    for (int i=0;i<20;i++){
      int m = t + 256*i;
      if (m < NN){
        float4 q = v1q[m];
        float d2 = fmaf(mx, q.x, fmaf(my2, q.y, fmaf(mz, q.z, sa + q.w)));
        unsigned int u = __float_as_uint(d2);
        u = ((int)u < 0) ? ~u : (u ^ 0x80000000u);
        if (u <= tau){
          int pos = atomicAdd(&scnt, 1);
          if (pos < TKCAND)
            cand[pos] = ((unsigned long long)u << 13) | (unsigned int)m;
        }
      }
    }
  }
  __syncthreads();
  int cnt = scnt; if (cnt > TKCAND) cnt = TKCAND;

  {
    unsigned long long kv0 = (t < cnt) ? cand[t] : ~0ull;
    unsigned long long kv1 = (t+256 < cnt) ? cand[t+256] : ~0ull;
    int r0 = 0, r1 = 0;
    for (int j=0; j<cnt; ++j){
      unsigned long long cj = cand[j];
      r0 += (cj < kv0);
      r1 += (cj < kv1);
    }
    if (t < cnt && r0 < kk)      sel[r0] = (int)(kv0 & 8191ull);
    if (t+256 < cnt && r1 < kk)  sel[r1] = (int)(kv1 & 8191ull);
  }
  __syncthreads();

  int c = t & 127;
  int rh = t >> 7;
  const float* f1n = feat1 + (size_t)row*CC;
  float e = f1n[c];
  float acc = 0.f;
  for (int r=rh; r<kk; r+=2){
    const float* g = feat1 + ((size_t)b*NN + sel[r])*CC;
    float d = g[c]-e;
    acc = fmaf(d,d,acc);
  }
  acc = wave_sum(acc);
  if (lane==0) rs[wid] = acc;
  __syncthreads();
  if (t==0){
    float s = (rs[0]+rs[1])+(rs[2]+rs[3]);
    atomicAdd(((double*)(ws+OFF_ACC)) + 128 + (blockIdx.x & 63), (double)s);
  }
}

// ---------------- proj2img stats ----------------
__global__ void k_imgstats(const float* __restrict__ verts2, const float* __restrict__ imgoff,
                           float* __restrict__ ws) {
  __shared__ float r0[4], r1[4], r2[4], r3[4];
  __shared__ float sgs, smnx, smny;
  int img = blockIdx.x >> 2, b = blockIdx.x & 3;
  const float* pc = (img==0) ? (ws + OFF_V12 + (size_t)b*NN*3) : (verts2 + (size_t)b*NN*3);
  int lane = threadIdx.x & 63, wid = threadIdx.x >> 6;
  float mnx=INFINITY, mxx=-INFINITY, mny=INFINITY, mxy=-INFINITY;
  for (int n = threadIdx.x; n < NN; n += 256) {
    float x = pc[(size_t)n*3], y = pc[(size_t)n*3+1];
    mnx=fminf(mnx,x); mxx=fmaxf(mxx,x); mny=fminf(mny,y); mxy=fmaxf(mxy,y);
  }
#pragma unroll
  for (int off=32; off; off>>=1) {
    mnx=fminf(mnx,__shfl_xor(mnx,off)); mxx=fmaxf(mxx,__shfl_xor(mxx,off));
    mny=fminf(mny,__shfl_xor(mny,off)); mxy=fmaxf(mxy,__shfl_xor(mxy,off));
  }
  if (lane==0){ r0[wid]=mnx; r1[wid]=mxx; r2[wid]=mny; r3[wid]=mxy; }
  __syncthreads();
  float* st = ws + OFF_STATS + (size_t)(img*4+b)*16;
  if (threadIdx.x==0){
    mnx=fminf(fminf(r0[0],r0[1]),fminf(r0[2],r0[3]));
    mxx=fmaxf(fmaxf(r1[0],r1[1]),fmaxf(r1[2],r1[3]));
    mny=fminf(fminf(r2[0],r2[1]),fminf(r2[2],r2[3]));
    mxy=fmaxf(fmaxf(r3[0],r3[1]),fmaxf(r3[2],r3[3]));
    float gs = fmaxf(mxx-mnx, mxy-mny) / 221.0f;
    sgs=gs; smnx=mnx; smny=mny;
    st[0]=mnx; st[1]=mxx; st[2]=mny; st[3]=mxy; st[4]=gs;
  }
  __syncthreads();
  float gs=sgs, bx=smnx, by=smny;
  float fmnx=INFINITY, fmxx=-INFINITY, fmny=INFINITY, fmxy=-INFINITY;
  for (int n = threadIdx.x; n < NN; n += 256) {
    float fx = floorf((pc[(size_t)n*3]-bx)/gs);
    float fy = floorf((pc[(size_t)n*3+1]-by)/gs);
    fmnx=fminf(fmnx,fx); fmxx=fmaxf(fmxx,fx); fmny=fminf(fmny,fy); fmxy=fmaxf(fmxy,fy);
  }
#pragma unroll
  for (int off=32; off; off>>=1) {
    fmnx=fminf(fmnx,__shfl_xor(fmnx,off)); fmxx=fmaxf(fmxx,__shfl_xor(fmxx,off));
    fmny=fminf(fmny,__shfl_xor(fmny,off)); fmxy=fmaxf(fmxy,__shfl_xor(fmxy,off));
  }
  __syncthreads();
  if (lane==0){ r0[wid]=fmnx; r1[wid]=fmxx; r2[wid]=fmny; r3[wid]=fmxy; }
  __syncthreads();
  if (threadIdx.x==0){
    fmnx=fminf(fminf(r0[0],r0[1]),fminf(r0[2],r0[3]));
    fmxx=fmaxf(fmaxf(r1[0],r1[1]),fmaxf(r1[2],r1[3]));
    fmny=fminf(fminf(r2[0],r2[1]),fminf(r2[2],r2[3]));
    fmxy=fmaxf(fmaxf(r3[0],r3[1]),fmaxf(r3[2],r3[3]));
    float omnx=INFINITY, omxx=-INFINITY, omny=INFINITY, omxy=-INFINITY;
    for (int l=0;l<25;l++){
      float ox=imgoff[l*2], oy=imgoff[l*2+1];
      omnx=fminf(omnx,ox); omxx=fmaxf(omxx,ox); omny=fminf(omny,oy); omxy=fmaxf(omxy,oy);
    }
    float cx = floorf(((fmxx+omxx+1.0f)+(fmnx+omnx+1.0f))*0.5f);
    float cy = floorf(((fmxy+omxy+1.0f)+(fmny+omny+1.0f))*0.5f);
    st[5] = (112.0f - cx) - 1.0f;
    st[6] = (112.0f - cy) - 1.0f;
  }
}

// ---------------- scatter z into both images ----------------
__global__ void k_scatter(const float* __restrict__ verts2, const float* __restrict__ imgoff,
                          float* __restrict__ ws) {
  int t = blockIdx.x*blockDim.x + threadIdx.x;
  if (t >= 2*BB*NN) return;
  int img = t / (BB*NN); int r = t - img*(BB*NN); int b = r / NN;
  const float* pc = (img==0) ? (ws + OFF_V12) : verts2;
  float x = pc[(size_t)r*3], y = pc[(size_t)r*3+1], z = pc[(size_t)r*3+2];
  const float* st = ws + OFF_STATS + (size_t)(img*4+b)*16;
  float mnx=st[0], mny=st[2], gs=st[4], offx=st[5], offy=st[6];
  float bx = floorf((x-mnx)/gs) + 1.0f + offx;
  float by = floorf((y-mny)/gs) + 1.0f + offy;
  float* im = ws + (img==0?OFF_IMG1:OFF_IMG2) + (size_t)b*IMGP;
#pragma unroll
  for (int l=0;l<25;l++){
    float vx = bx + imgoff[l*2], vy = by + imgoff[l*2+1];
    vx += (vx<0.f?1.f:0.f) - (vx>223.f?1.f:0.f);
    vy += (vy<0.f?1.f:0.f) - (vy>223.f?1.f:0.f);
    vx = fminf(fmaxf(vx,0.f),223.f); vy = fminf(fmaxf(vy,0.f),223.f);
    int flat = (int)(vx*224.f + vy);
    atomicAdd(im + flat, z);
  }
}

// ---------------- image loss ----------------
__global__ void k_imgloss(float* __restrict__ ws) {
  int i = blockIdx.x*blockDim.x + threadIdx.x;
  float v = 0.f;
  if (i < BB*IMGP) {
    float a = ws[OFF_IMG1+i], c = ws[OFF_IMG2+i];
    float sa = 1.f/(1.f+expf(-a)), sc = 1.f/(1.f+expf(-c));
    float d = sa - sc; v = d*d;
  }
  v = wave_sum(v);
  if ((threadIdx.x&63)==0)
    atomicAdd(((double*)(ws+OFF_ACC)) + 64 + (blockIdx.x & 63), (double)v);
}

// ---------------- finalize ----------------
__global__ void k_final(const int* __restrict__ kptr, const float* __restrict__ ws, float* __restrict__ out) {
  const double* acc = (const double*)(ws+OFF_ACC);
  int kk = *kptr; if (kk > 16) kk = 16; if (kk < 1) kk = 1;
  double a0=0.0, a1=0.0, a2=0.0;
  for (int j=0;j<64;j++){ a0 += acc[j]; a1 += acc[64+j]; a2 += acc[128+j]; }
  double srl = a0 / (double)(BB*NN);
  double img = a1 / ((double)BB*IMGP);
  double df  = a2 / ((double)BB*NN*kk*CC);
  out[0] = (float)(srl + img + df);
}

extern "C" void kernel_launch(void* const* d_in, const int* in_sizes, int n_in,
                              void* d_out, int out_size, void* d_ws, size_t ws_size,
                              hipStream_t stream) {
  (void)in_sizes; (void)n_in; (void)out_size;
  const float* verts1 = (const float*)d_in[0];
  const float* verts2 = (const float*)d_in[1];
  const float* feat1  = (const float*)d_in[2];
  const float* feat2  = (const float*)d_in[3];
  const float* imgoff = (const float*)d_in[4];
  const int*   kptr   = (const int*)d_in[5];
  float* ws  = (float*)d_ws;
  float* out = (float*)d_out;
  bool pre = ws_size >= WS_NEED_PRE;

  hipMemsetAsync(ws + ZERO_START, 0, (size_t)ZERO_FLOATS*sizeof(float), stream);

  k_norms<<<(BB*NN+255)/256, 256, 0, stream>>>(verts1, verts2, feat1, feat2, ws);

  dim3 gC(NG, BB);
  k_conv<<<gC, 256, 0, stream>>>(feat2, ws);

  dim3 gA(RBLK, SPLITS, BB);
  if (pre) {
    dim3 g1(RBLK, BB);
    k_conv1<<<g1, 256, 0, stream>>>(feat1, ws);
    k_stageA_pre<<<gA, 256, 0, stream>>>(ws);
  } else {
    k_stageA_fb<<<gA, 256, 0, stream>>>(feat1, ws);
  }
  k_combine<<<(BB*NN+255)/256, 256, 0, stream>>>(ws);

  dim3 gS((NN+15)/16, BB);
  k_selfrec<<<gS, 256, 0, stream>>>(ws);
  k_topk<<<BB*NN, 256, 0, stream>>>(feat1, kptr, ws);

  k_imgstats<<<8, 256, 0, stream>>>(verts2, imgoff, ws);
  k_scatter<<<(2*BB*NN+255)/256, 256, 0, stream>>>(verts2, imgoff, ws);
  k_imgloss<<<(BB*IMGP+255)/256, 256, 0, stream>>>(ws);

  k_final<<<1,1,0,stream>>>(kptr, ws, out);
}

// Round 10
// 542.444 us; speedup vs baseline: 1.8449x; 1.8449x over previous
//
#include <hip/hip_runtime.h>
#include <math.h>

#define BB 4
#define NN 4995
#define CC 128
#define IMG 224
#define IMGP (IMG*IMG)
#define ALPHA_F 100.0f
#define SPLITS 8
#define COLS_PER_SPLIT 640   // 32-aligned; 8*640=5120 >= 4995
#define RBLK 40              // ceil(4995/128)
#define NG 158               // col groups of 32 (incl. 1 pad group)
#define TKCAND 512
#define NTAP (2*BB*NN*25)    // 999000 scatter taps
#define NREP 4

// ws layout in float units
#define OFF_V12    0            // 59940
#define OFF_FN1    60000        // 19980
#define OFF_V1Q    81000        // 79920 {x,y,z,|v1|^2}
#define OFF_V2Q    161000       // 79920 {x,y,z,|v2|^2}
#define OFF_C2Q    241000       // 79920 {x,y,z,|f2|^2}
#define OFF_PART   321000       // 19980*8*5 = 799200 -> ends 1120200
#define OFF_IMG1   1121000      // 200704
#define OFF_IMG2   1321704      // 200704 -> ends 1522408
#define OFF_ACC    1522408      // 3*64 f64 = 384 floats (byte 6089632, 8-aligned)
#define OFF_STATS  1522792      // 128 -> ends 1522920
#define OFF_F2H    1523000      // 4*158*4096 shorts = 1294336 floats
#define OFF_F2L    2818000      // 1294336 floats -> ends 4112336 (16.45MB)
#define OFF_IMGR   4113000      // 4 reps * 2 imgs * 4 b * 50176 = 1605632 floats -> ends 5718632
#define WS_NEED_REP ((size_t)5719000*sizeof(float))
#define ZERO_START OFF_IMG1
#define ZERO_FLOATS (1522920 - OFF_IMG1)

typedef short v8s  __attribute__((ext_vector_type(8)));
typedef float v16f __attribute__((ext_vector_type(16)));

__device__ __forceinline__ float wave_min(float v){
#pragma unroll
  for (int off=32; off; off>>=1) v = fminf(v, __shfl_xor(v, off));
  return v;
}
__device__ __forceinline__ float wave_sum(float v){
#pragma unroll
  for (int off=32; off; off>>=1) v += __shfl_xor(v, off);
  return v;
}

// pack top-16 bits (bf16 truncation) of two floats: (hi16(b)<<16)|hi16(a)
__device__ __forceinline__ int pack_bf_hi(float a, float b){
  return (int)__builtin_amdgcn_perm(__float_as_uint(b), __float_as_uint(a), 0x07060302u);
}

__device__ __forceinline__ void cvt_hilo(float4 a, float4 c, int4& hi, int4& lo){
  float hx=__uint_as_float(__float_as_uint(a.x)&0xffff0000u);
  float hy=__uint_as_float(__float_as_uint(a.y)&0xffff0000u);
  float hz=__uint_as_float(__float_as_uint(a.z)&0xffff0000u);
  float hw=__uint_as_float(__float_as_uint(a.w)&0xffff0000u);
  float gx=__uint_as_float(__float_as_uint(c.x)&0xffff0000u);
  float gy=__uint_as_float(__float_as_uint(c.y)&0xffff0000u);
  float gz=__uint_as_float(__float_as_uint(c.z)&0xffff0000u);
  float gw=__uint_as_float(__float_as_uint(c.w)&0xffff0000u);
  hi = make_int4(pack_bf_hi(a.x,a.y), pack_bf_hi(a.z,a.w),
                 pack_bf_hi(c.x,c.y), pack_bf_hi(c.z,c.w));
  lo = make_int4(pack_bf_hi(a.x-hx,a.y-hy), pack_bf_hi(a.z-hz,a.w-hw),
                 pack_bf_hi(c.x-gx,c.y-gy), pack_bf_hi(c.z-gz,c.w-gw));
}

// ---------------- norms + packed quads ----------------
__global__ void k_norms(const float* __restrict__ verts1, const float* __restrict__ verts2,
                        const float* __restrict__ feat1, const float* __restrict__ feat2,
                        float* __restrict__ ws) {
  int i = blockIdx.x*blockDim.x + threadIdx.x;
  if (i >= BB*NN) return;
  float x=verts1[(size_t)i*3], y=verts1[(size_t)i*3+1], z=verts1[(size_t)i*3+2];
  ((float4*)(ws+OFF_V1Q))[i] = make_float4(x,y,z, x*x+y*y+z*z);
  float x2=verts2[(size_t)i*3], y2=verts2[(size_t)i*3+1], z2=verts2[(size_t)i*3+2];
  ((float4*)(ws+OFF_V2Q))[i] = make_float4(x2,y2,z2, x2*x2+y2*y2+z2*z2);
  {
    const float4* f = (const float4*)(feat2 + (size_t)i*CC);
    float s0=0.f,s1=0.f,s2=0.f,s3=0.f;
#pragma unroll
    for (int k=0;k<CC/4;k++){ float4 t=f[k];
      s0=fmaf(t.x,t.x,s0); s1=fmaf(t.y,t.y,s1); s2=fmaf(t.z,t.z,s2); s3=fmaf(t.w,t.w,s3); }
    ((float4*)(ws+OFF_C2Q))[i] = make_float4(x2,y2,z2, (s0+s1)+(s2+s3));
  }
  {
    const float4* f = (const float4*)(feat1 + (size_t)i*CC);
    float s0=0.f,s1=0.f,s2=0.f,s3=0.f;
#pragma unroll
    for (int k=0;k<CC/4;k++){ float4 t=f[k];
      s0=fmaf(t.x,t.x,s0); s1=fmaf(t.y,t.y,s1); s2=fmaf(t.z,t.z,s2); s3=fmaf(t.w,t.w,s3); }
    ws[OFF_FN1+i] = (s0+s1)+(s2+s3);
  }
}

// ---------------- pre-convert feat2 -> tiled bf16 hi/lo ----------------
// layout [b][g][kt4][kh2][half2][c32][j8], strides (shorts): j=1,c32=8,half=256,kh=512,kt=1024,g=4096
__global__ __launch_bounds__(256) void k_conv(const float* __restrict__ feat2, float* __restrict__ ws) {
  int g = blockIdx.x, b = blockIdx.y;
  int t = threadIdx.x;
  int q = t >> 5, c32 = t & 31;
  int col = g*32 + c32; if (col > NN-1) col = NN-1;
  const float4* src = (const float4*)(feat2 + ((size_t)(b*NN + col))*CC) + q*4;
  float4 v0 = src[0], v1 = src[1], v2 = src[2], v3 = src[3];
  short* f2h = (short*)(ws + OFF_F2H);
  short* f2l = (short*)(ws + OFF_F2L);
  size_t base = ((size_t)(b*NG + g))*4096 + (size_t)q*512 + c32*8;
  int4 hi, lo;
  cvt_hilo(v0, v1, hi, lo);
  *(int4*)&f2h[base] = hi;  *(int4*)&f2l[base] = lo;
  cvt_hilo(v2, v3, hi, lo);
  *(int4*)&f2h[base + 256] = hi;  *(int4*)&f2l[base + 256] = lo;
}

// ---------------- stage A: swapped-operand MFMA GEMM + in-lane online softmax ----------------
__global__ __launch_bounds__(256) void k_stageA(const float* __restrict__ feat1,
      float* __restrict__ ws) {
  __shared__ __align__(16) short Ah[4096], Al[4096];
  __shared__ __align__(16) short Bh[2048], Bl[2048];
  __shared__ __align__(16) float colq[64*4];

  int rblk  = blockIdx.x;
  int split = blockIdx.y;
  int b     = blockIdx.z;
  int rowBase = rblk*128;
  int colBase = split*COLS_PER_SPLIT;
  int colEnd  = colBase + COLS_PER_SPLIT; if (colEnd > NN) colEnd = NN;
  int nct = (colEnd - colBase + 63) >> 6;

  int t    = threadIdx.x;
  int w    = t >> 6;
  int lane = t & 63;
  int half = lane >> 5;
  int m32  = lane & 31;

  const float* f1b = feat1 + (size_t)b*NN*CC;
  const short* f2h = (const short*)(ws + OFF_F2H);
  const short* f2l = (const short*)(ws + OFF_F2L);
  const float4* c2q = (const float4*)(ws + OFF_C2Q) + (size_t)b*NN;

  int nrow = rowBase + w*32 + m32;
  int nclamp = nrow > NN-1 ? NN-1 : nrow;
  float sn = ws[OFF_FN1 + (size_t)b*NN + nclamp];

  int sr = t >> 1, skh = t & 1;
  int srow = rowBase + sr; if (srow > NN-1) srow = NN-1;
  int sgg = sr >> 5, sr32 = sr & 31;
  const float4* aSrcBase = (const float4*)(f1b + (size_t)srow*CC);
  size_t aDst = (size_t)sgg*1024 + (size_t)skh*512 + sr32*8;

  int scg = t >> 7;
  size_t bDstOff = (size_t)scg*1024 + (t & 127)*8;

  float mm = -INFINITY, S = 0.f, Vx = 0.f, Vy = 0.f, Vz = 0.f;

  for (int ci = 0; ci < nct; ci++){
    int ctBase = colBase + ci*64;
    int g0 = ctBase >> 5;
    __syncthreads();
    if (t < 64){
      int c = ctBase + t; if (c > NN-1) c = NN-1;
      *(float4*)&colq[t*4] = c2q[c];
    }
    v16f acc0, acc1;
#pragma unroll
    for (int i=0;i<16;i++){ acc0[i]=0.f; acc1[i]=0.f; }

#pragma unroll 1
    for (int kt = 0; kt < 4; kt++){
      __syncthreads();
      {
        size_t gsrc = ((size_t)(b*NG + g0 + scg))*4096 + (size_t)kt*1024 + (t & 127)*8;
        int4 vh = *(const int4*)&f2h[gsrc];
        int4 vl = *(const int4*)&f2l[gsrc];
        *(int4*)&Bh[bDstOff] = vh;
        *(int4*)&Bl[bDstOff] = vl;
      }
      {
        const float4* s4 = aSrcBase + kt*8 + skh*4;
        float4 v0=s4[0], v1=s4[1], v2=s4[2], v3=s4[3];
        int4 hi, lo;
        cvt_hilo(v0, v1, hi, lo);
        *(int4*)&Ah[aDst] = hi;  *(int4*)&Al[aDst] = lo;
        cvt_hilo(v2, v3, hi, lo);
        *(int4*)&Ah[aDst + 256] = hi;  *(int4*)&Al[aDst + 256] = lo;
      }
      __syncthreads();
#pragma unroll
      for (int kh=0; kh<2; kh++){
        size_t fo = (size_t)kh*512 + (size_t)half*256 + m32*8;
        v8s b1h = *(const v8s*)&Ah[(size_t)w*1024 + fo];
        v8s b1l = *(const v8s*)&Al[(size_t)w*1024 + fo];
        v8s a0h = *(const v8s*)&Bh[fo];
        v8s a0l = *(const v8s*)&Bl[fo];
        v8s a1h = *(const v8s*)&Bh[1024 + fo];
        v8s a1l = *(const v8s*)&Bl[1024 + fo];
        acc0 = __builtin_amdgcn_mfma_f32_32x32x16_bf16(a0h, b1h, acc0, 0,0,0);
        acc0 = __builtin_amdgcn_mfma_f32_32x32x16_bf16(a0h, b1l, acc0, 0,0,0);
        acc0 = __builtin_amdgcn_mfma_f32_32x32x16_bf16(a0l, b1h, acc0, 0,0,0);
        acc1 = __builtin_amdgcn_mfma_f32_32x32x16_bf16(a1h, b1h, acc1, 0,0,0);
        acc1 = __builtin_amdgcn_mfma_f32_32x32x16_bf16(a1h, b1l, acc1, 0,0,0);
        acc1 = __builtin_amdgcn_mfma_f32_32x32x16_bf16(a1l, b1h, acc1, 0,0,0);
      }
    }

    float Mt = -INFINITY;
#pragma unroll
    for (int reg=0; reg<16; reg++){
      int cp0 = (reg&3) + 8*(reg>>2) + 4*half;
      float f0 = colq[cp0*4+3];
      float d0 = fmaf(-2.f, acc0[reg], sn) + f0;
      float l0 = (ctBase+cp0 < colEnd) ? (-ALPHA_F*sqrtf(fmaxf(d0,1e-12f))) : -INFINITY;
      acc0[reg] = l0; Mt = fmaxf(Mt, l0);
      int cp1 = cp0 + 32;
      float f1v = colq[cp1*4+3];
      float d1 = fmaf(-2.f, acc1[reg], sn) + f1v;
      float l1 = (ctBase+cp1 < colEnd) ? (-ALPHA_F*sqrtf(fmaxf(d1,1e-12f))) : -INFINITY;
      acc1[reg] = l1; Mt = fmaxf(Mt, l1);
    }
    float mn = fmaxf(mm, Mt);
    float sc = __expf(mm - mn);
    float se=0.f, sx=0.f, sy=0.f, sz=0.f;
#pragma unroll
    for (int reg=0; reg<16; reg++){
      int cp0 = (reg&3) + 8*(reg>>2) + 4*half;
      float4 q0 = *(const float4*)&colq[cp0*4];
      float e0 = __expf(acc0[reg] - mn);
      se += e0; sx=fmaf(e0,q0.x,sx); sy=fmaf(e0,q0.y,sy); sz=fmaf(e0,q0.z,sz);
      float4 q1 = *(const float4*)&colq[(cp0+32)*4];
      float e1 = __expf(acc1[reg] - mn);
      se += e1; sx=fmaf(e1,q1.x,sx); sy=fmaf(e1,q1.y,sy); sz=fmaf(e1,q1.z,sz);
    }
    S  = fmaf(S,  sc, se);
    Vx = fmaf(Vx, sc, sx);
    Vy = fmaf(Vy, sc, sy);
    Vz = fmaf(Vz, sc, sz);
    mm = mn;
  }

  {
    float m2  = __shfl_xor(mm, 32);
    float S2  = __shfl_xor(S,  32);
    float Vx2 = __shfl_xor(Vx, 32);
    float Vy2 = __shfl_xor(Vy, 32);
    float Vz2 = __shfl_xor(Vz, 32);
    float M = fmaxf(mm, m2);
    float c1 = __expf(mm - M), c2 = __expf(m2 - M);
    float Sf  = S*c1  + S2*c2;
    float Vxf = Vx*c1 + Vx2*c2;
    float Vyf = Vy*c1 + Vy2*c2;
    float Vzf = Vz*c1 + Vz2*c2;
    if (half==0 && nrow < NN){
      float* p = ws + OFF_PART + ((size_t)(b*NN+nrow)*SPLITS + split)*5;
      p[0]=M; p[1]=Sf; p[2]=Vxf; p[3]=Vyf; p[4]=Vzf;
    }
  }
}

// ---------------- combine partials -> verts12 ----------------
__global__ void k_combine(float* __restrict__ ws) {
  int row = blockIdx.x*blockDim.x + threadIdx.x;
  if (row >= BB*NN) return;
  const float* p = ws + OFF_PART + (size_t)row*SPLITS*5;
  float mm = -INFINITY;
#pragma unroll
  for (int s=0;s<SPLITS;s++) mm = fmaxf(mm, p[s*5]);
  float S=0.f,Vx=0.f,Vy=0.f,Vz=0.f;
#pragma unroll
  for (int s=0;s<SPLITS;s++){
    float sc = expf(p[s*5]-mm);
    S  += p[s*5+1]*sc; Vx += p[s*5+2]*sc; Vy += p[s*5+3]*sc; Vz += p[s*5+4]*sc;
  }
  ws[OFF_V12+(size_t)row*3+0]=Vx/S;
  ws[OFF_V12+(size_t)row*3+1]=Vy/S;
  ws[OFF_V12+(size_t)row*3+2]=Vz/S;
}

// ---------------- self-rec: 4 rows/wave, 16 rows/block ----------------
__global__ __launch_bounds__(256) void k_selfrec(float* __restrict__ ws) {
  int rblk = blockIdx.x, b = blockIdx.y;
  int lane = threadIdx.x & 63, w = threadIdx.x >> 6;
  int r0 = rblk*16 + w*4;
  const float4* v2q = (const float4*)(ws + OFF_V2Q) + (size_t)b*NN;
  const float* v12 = ws + OFF_V12 + (size_t)b*NN*3;
  float xr[4], yr[4], zr[4], sar[4]; bool val[4];
#pragma unroll
  for (int j=0;j<4;j++){
    int n = r0+j; val[j] = (n < NN); int nc = val[j] ? n : NN-1;
    xr[j]=v12[(size_t)nc*3]; yr[j]=v12[(size_t)nc*3+1]; zr[j]=v12[(size_t)nc*3+2];
    sar[j]=xr[j]*xr[j]+yr[j]*yr[j]+zr[j]*zr[j];
  }
  float mn0=INFINITY, mn1=INFINITY, mn2=INFINITY, mn3=INFINITY;
  for (int m=lane; m<NN; m+=64) {
    float4 q = v2q[m];
    mn0 = fminf(mn0, fmaf(-2.0f, xr[0]*q.x + yr[0]*q.y + zr[0]*q.z, sar[0]) + q.w);
    mn1 = fminf(mn1, fmaf(-2.0f, xr[1]*q.x + yr[1]*q.y + zr[1]*q.z, sar[1]) + q.w);
    mn2 = fminf(mn2, fmaf(-2.0f, xr[2]*q.x + yr[2]*q.y + zr[2]*q.z, sar[2]) + q.w);
    mn3 = fminf(mn3, fmaf(-2.0f, xr[3]*q.x + yr[3]*q.y + zr[3]*q.z, sar[3]) + q.w);
  }
  mn0 = wave_min(mn0); mn1 = wave_min(mn1); mn2 = wave_min(mn2); mn3 = wave_min(mn3);
  float s = (val[0]?mn0:0.f) + (val[1]?mn1:0.f) + (val[2]?mn2:0.f) + (val[3]?mn3:0.f);
  if (lane==0)
    atomicAdd(((double*)(ws+OFF_ACC)) + ((rblk*4 + w) & 63), (double)s);
}

// ---------------- top-k: 4 rows/block, ballot-radix threshold + rank-count selection ----------------
__global__ __launch_bounds__(256) void k_topk(const float* __restrict__ feat1,
        const int* __restrict__ kptr, float* __restrict__ ws) {
  __shared__ unsigned int keybuf[256];
  __shared__ unsigned long long cand[TKCAND];
  __shared__ int scnt;
  __shared__ int sel[16];
  __shared__ float rs[4];
  int t = threadIdx.x;
  int lane = t & 63, wid = t >> 6;
  int b = blockIdx.y;
  int n0 = blockIdx.x*4;
  int kk = *kptr; if (kk > 16) kk = 16; if (kk < 1) kk = 1;

  const float4* v1q = (const float4*)(ws + OFF_V1Q) + (size_t)b*NN;
  float mx[4], my2[4], mz[4], sa[4];
#pragma unroll
  for (int j=0;j<4;j++){
    int n = n0+j; if (n > NN-1) n = NN-1;
    float4 me = v1q[n];
    mx[j]=-2.0f*me.x; my2[j]=-2.0f*me.y; mz[j]=-2.0f*me.z; sa[j]=me.w;
  }

  // phase 1: per-thread min key for each of the 4 rows (shared q loads)
  unsigned int mykey[4] = {0xFFFFFFFFu,0xFFFFFFFFu,0xFFFFFFFFu,0xFFFFFFFFu};
#pragma unroll
  for (int i=0;i<20;i++){
    int m = t + 256*i;
    if (m < NN){
      float4 q = v1q[m];
#pragma unroll
      for (int j=0;j<4;j++){
        float d2 = fmaf(mx[j], q.x, fmaf(my2[j], q.y, fmaf(mz[j], q.z, sa[j] + q.w)));
        unsigned int u = __float_as_uint(d2);
        u = ((int)u < 0) ? ~u : (u ^ 0x80000000u);
        mykey[j] = u < mykey[j] ? u : mykey[j];
      }
    }
  }

  float mse = 0.f;
  for (int j=0;j<4;j++){
    int n = n0+j;
    if (n >= NN) break;           // uniform across block
    __syncthreads();              // protect keybuf/cand/sel reuse
    keybuf[t] = mykey[j];
    if (t==0) scnt = 0;
    __syncthreads();

    unsigned int tau;
    {
      unsigned int k0 = keybuf[lane];
      unsigned int k1 = keybuf[64+lane];
      unsigned int k2 = keybuf[128+lane];
      unsigned int k3 = keybuf[192+lane];
      unsigned int prefix = 0;
      for (int bit=31; bit>=0; --bit){
        unsigned int piv = prefix | (1u<<bit);
        int c = __popcll(__ballot(k0 < piv)) + __popcll(__ballot(k1 < piv))
              + __popcll(__ballot(k2 < piv)) + __popcll(__ballot(k3 < piv));
        if (c < kk) prefix = piv;
      }
      tau = prefix;
    }

    if (mykey[j] <= tau){
#pragma unroll
      for (int i=0;i<20;i++){
        int m = t + 256*i;
        if (m < NN){
          float4 q = v1q[m];
          float d2 = fmaf(mx[j], q.x, fmaf(my2[j], q.y, fmaf(mz[j], q.z, sa[j] + q.w)));
          unsigned int u = __float_as_uint(d2);
          u = ((int)u < 0) ? ~u : (u ^ 0x80000000u);
          if (u <= tau){
            int pos = atomicAdd(&scnt, 1);
            if (pos < TKCAND)
              cand[pos] = ((unsigned long long)u << 13) | (unsigned int)m;
          }
        }
      }
    }
    __syncthreads();
    int cnt = scnt; if (cnt > TKCAND) cnt = TKCAND;

    {
      unsigned long long kv0 = (t < cnt) ? cand[t] : ~0ull;
      unsigned long long kv1 = (t+256 < cnt) ? cand[t+256] : ~0ull;
      int r0 = 0, r1 = 0;
      for (int q2=0; q2<cnt; ++q2){
        unsigned long long cj = cand[q2];
        r0 += (cj < kv0);
        r1 += (cj < kv1);
      }
      if (t < cnt && r0 < kk)      sel[r0] = (int)(kv0 & 8191ull);
      if (t+256 < cnt && r1 < kk)  sel[r1] = (int)(kv1 & 8191ull);
    }
    __syncthreads();

    int c = t & 127;
    int rh = t >> 7;
    const float* f1n = feat1 + ((size_t)b*NN + n)*CC;
    float e = f1n[c];
    for (int r=rh; r<kk; r+=2){
      const float* g = feat1 + ((size_t)b*NN + sel[r])*CC;
      float d = g[c]-e;
      mse = fmaf(d,d,mse);
    }
  }

  float acc = wave_sum(mse);
  if (lane==0) rs[wid] = acc;
  __syncthreads();
  if (t==0){
    float s = (rs[0]+rs[1])+(rs[2]+rs[3]);
    atomicAdd(((double*)(ws+OFF_ACC)) + 128 + ((blockIdx.x + b) & 63), (double)s);
  }
}

// ---------------- proj2img stats ----------------
__global__ void k_imgstats(const float* __restrict__ verts2, const float* __restrict__ imgoff,
                           float* __restrict__ ws) {
  __shared__ float r0[4], r1[4], r2[4], r3[4];
  __shared__ float sgs, smnx, smny;
  int img = blockIdx.x >> 2, b = blockIdx.x & 3;
  const float* pc = (img==0) ? (ws + OFF_V12 + (size_t)b*NN*3) : (verts2 + (size_t)b*NN*3);
  int lane = threadIdx.x & 63, wid = threadIdx.x >> 6;
  float mnx=INFINITY, mxx=-INFINITY, mny=INFINITY, mxy=-INFINITY;
  for (int n = threadIdx.x; n < NN; n += 256) {
    float x = pc[(size_t)n*3], y = pc[(size_t)n*3+1];
    mnx=fminf(mnx,x); mxx=fmaxf(mxx,x); mny=fminf(mny,y); mxy=fmaxf(mxy,y);
  }
#pragma unroll
  for (int off=32; off; off>>=1) {
    mnx=fminf(mnx,__shfl_xor(mnx,off)); mxx=fmaxf(mxx,__shfl_xor(mxx,off));
    mny=fminf(mny,__shfl_xor(mny,off)); mxy=fmaxf(mxy,__shfl_xor(mxy,off));
  }
  if (lane==0){ r0[wid]=mnx; r1[wid]=mxx; r2[wid]=mny; r3[wid]=mxy; }
  __syncthreads();
  float* st = ws + OFF_STATS + (size_t)(img*4+b)*16;
  if (threadIdx.x==0){
    mnx=fminf(fminf(r0[0],r0[1]),fminf(r0[2],r0[3]));
    mxx=fmaxf(fmaxf(r1[0],r1[1]),fmaxf(r1[2],r1[3]));
    mny=fminf(fminf(r2[0],r2[1]),fminf(r2[2],r2[3]));
    mxy=fmaxf(fmaxf(r3[0],r3[1]),fmaxf(r3[2],r3[3]));
    float gs = fmaxf(mxx-mnx, mxy-mny) / 221.0f;
    sgs=gs; smnx=mnx; smny=mny;
    st[0]=mnx; st[1]=mxx; st[2]=mny; st[3]=mxy; st[4]=gs;
  }
  __syncthreads();
  float gs=sgs, bx=smnx, by=smny;
  float fmnx=INFINITY, fmxx=-INFINITY, fmny=INFINITY, fmxy=-INFINITY;
  for (int n = threadIdx.x; n < NN; n += 256) {
    float fx = floorf((pc[(size_t)n*3]-bx)/gs);
    float fy = floorf((pc[(size_t)n*3+1]-by)/gs);
    fmnx=fminf(fmnx,fx); fmxx=fmaxf(fmxx,fx); fmny=fminf(fmny,fy); fmxy=fmaxf(fmxy,fy);
  }
#pragma unroll
  for (int off=32; off; off>>=1) {
    fmnx=fminf(fmnx,__shfl_xor(fmnx,off)); fmxx=fmaxf(fmxx,__shfl_xor(fmxx,off));
    fmny=fminf(fmny,__shfl_xor(fmny,off)); fmxy=fmaxf(fmxy,__shfl_xor(fmxy,off));
  }
  __syncthreads();
  if (lane==0){ r0[wid]=fmnx; r1[wid]=fmxx; r2[wid]=fmny; r3[wid]=fmxy; }
  __syncthreads();
  if (threadIdx.x==0){
    fmnx=fminf(fminf(r0[0],r0[1]),fminf(r0[2],r0[3]));
    fmxx=fmaxf(fmaxf(r1[0],r1[1]),fmaxf(r1[2],r1[3]));
    fmny=fminf(fminf(r2[0],r2[1]),fminf(r2[2],r2[3]));
    fmxy=fmaxf(fmaxf(r3[0],r3[1]),fmaxf(r3[2],r3[3]));
    float omnx=INFINITY, omxx=-INFINITY, omny=INFINITY, omxy=-INFINITY;
    for (int l=0;l<25;l++){
      float ox=imgoff[l*2], oy=imgoff[l*2+1];
      omnx=fminf(omnx,ox); omxx=fmaxf(omxx,ox); omny=fminf(omny,oy); omxy=fmaxf(omxy,oy);
    }
    float cx = floorf(((fmxx+omxx+1.0f)+(fmnx+omnx+1.0f))*0.5f);
    float cy = floorf(((fmxy+omxy+1.0f)+(fmny+omny+1.0f))*0.5f);
    st[5] = (112.0f - cx) - 1.0f;
    st[6] = (112.0f - cy) - 1.0f;
  }
}

// ---------------- scatter: 1 thread per (point,tap), replicated images ----------------
__global__ __launch_bounds__(256) void k_scatter(const float* __restrict__ verts2,
                          const float* __restrict__ imgoff,
                          float* __restrict__ ws, int nrep) {
  int g = blockIdx.x*256 + threadIdx.x;
  if (g >= NTAP) return;
  int p = g / 25; int l = g - p*25;
  int img = p / (BB*NN); int r = p - img*(BB*NN); int b = r / NN;
  const float* pc = (img==0) ? (ws + OFF_V12) : verts2;
  float x = pc[(size_t)r*3], y = pc[(size_t)r*3+1], z = pc[(size_t)r*3+2];
  const float* st = ws + OFF_STATS + (size_t)(img*4+b)*16;
  float mnx=st[0], mny=st[2], gs=st[4], offx=st[5], offy=st[6];
  float bx = floorf((x-mnx)/gs) + 1.0f + offx;
  float by = floorf((y-mny)/gs) + 1.0f + offy;
  float vx = bx + imgoff[l*2], vy = by + imgoff[l*2+1];
  vx += (vx<0.f?1.f:0.f) - (vx>223.f?1.f:0.f);
  vy += (vy<0.f?1.f:0.f) - (vy>223.f?1.f:0.f);
  vx = fminf(fmaxf(vx,0.f),223.f); vy = fminf(fmaxf(vy,0.f),223.f);
  int flat = (int)(vx*224.f + vy);
  float* im;
  if (nrep > 1)
    im = ws + OFF_IMGR + ((size_t)(((blockIdx.x & (nrep-1))*2 + img)*BB + b))*IMGP;
  else
    im = ws + (img==0?OFF_IMG1:OFF_IMG2) + (size_t)b*IMGP;
  atomicAdd(im + flat, z);
}

// ---------------- image loss (sums replicas) ----------------
__global__ void k_imgloss(float* __restrict__ ws, int nrep) {
  int i = blockIdx.x*blockDim.x + threadIdx.x;
  float v = 0.f;
  if (i < BB*IMGP) {
    float a, c;
    if (nrep > 1){
      a = 0.f; c = 0.f;
      for (int r=0; r<nrep; ++r){
        a += ws[OFF_IMGR + (size_t)(r*2+0)*BB*IMGP + i];
        c += ws[OFF_IMGR + (size_t)(r*2+1)*BB*IMGP + i];
      }
    } else {
      a = ws[OFF_IMG1+i]; c = ws[OFF_IMG2+i];
    }
    float sa = 1.f/(1.f+expf(-a)), sc = 1.f/(1.f+expf(-c));
    float d = sa - sc; v = d*d;
  }
  v = wave_sum(v);
  if ((threadIdx.x&63)==0)
    atomicAdd(((double*)(ws+OFF_ACC)) + 64 + (blockIdx.x & 63), (double)v);
}

// ---------------- finalize ----------------
__global__ void k_final(const int* __restrict__ kptr, const float* __restrict__ ws, float* __restrict__ out) {
  const double* acc = (const double*)(ws+OFF_ACC);
  int kk = *kptr; if (kk > 16) kk = 16; if (kk < 1) kk = 1;
  double a0=0.0, a1=0.0, a2=0.0;
  for (int j=0;j<64;j++){ a0 += acc[j]; a1 += acc[64+j]; a2 += acc[128+j]; }
  double srl = a0 / (double)(BB*NN);
  double img = a1 / ((double)BB*IMGP);
  double df  = a2 / ((double)BB*NN*kk*CC);
  out[0] = (float)(srl + img + df);
}

extern "C" void kernel_launch(void* const* d_in, const int* in_sizes, int n_in,
                              void* d_out, int out_size, void* d_ws, size_t ws_size,
                              hipStream_t stream) {
  (void)in_sizes; (void)n_in; (void)out_size;
  const float* verts1 = (const float*)d_in[0];
  const float* verts2 = (const float*)d_in[1];
  const float* feat1  = (const float*)d_in[2];
  const float* feat2  = (const float*)d_in[3];
  const float* imgoff = (const float*)d_in[4];
  const int*   kptr   = (const int*)d_in[5];
  float* ws  = (float*)d_ws;
  float* out = (float*)d_out;
  int nrep = (ws_size >= WS_NEED_REP) ? NREP : 1;

  hipMemsetAsync(ws + ZERO_START, 0, (size_t)ZERO_FLOATS*sizeof(float), stream);
  if (nrep > 1)
    hipMemsetAsync(ws + OFF_IMGR, 0, (size_t)NREP*2*BB*IMGP*sizeof(float), stream);

  k_norms<<<(BB*NN+255)/256, 256, 0, stream>>>(verts1, verts2, feat1, feat2, ws);

  dim3 gC(NG, BB);
  k_conv<<<gC, 256, 0, stream>>>(feat2, ws);

  dim3 gA(RBLK, SPLITS, BB);
  k_stageA<<<gA, 256, 0, stream>>>(feat1, ws);
  k_combine<<<(BB*NN+255)/256, 256, 0, stream>>>(ws);

  dim3 gS((NN+15)/16, BB);
  k_selfrec<<<gS, 256, 0, stream>>>(ws);

  dim3 gT((NN+3)/4, BB);
  k_topk<<<gT, 256, 0, stream>>>(feat1, kptr, ws);

  k_imgstats<<<8, 256, 0, stream>>>(verts2, imgoff, ws);
  k_scatter<<<(NTAP+255)/256, 256, 0, stream>>>(verts2, imgoff, ws, nrep);
  k_imgloss<<<(BB*IMGP+255)/256, 256, 0, stream>>>(ws, nrep);

  k_final<<<1,1,0,stream>>>(kptr, ws, out);
}